// Round 10
// baseline (179.029 us; speedup 1.0000x reference)
//
#include <hip/hip_runtime.h>
#include <hip/hip_bf16.h>

typedef __attribute__((ext_vector_type(8))) short short8;
typedef __attribute__((ext_vector_type(4))) short short4v;
typedef __attribute__((ext_vector_type(4))) float floatx4;
typedef unsigned short u16;

#define SCL_LOG2E 0.1803368801111204f  // (1/sqrt(64)) * log2(e)

__device__ inline u16 f2b(float f) {
  __hip_bfloat16 h = __float2bfloat16(f);
  union { __hip_bfloat16 h; u16 u; } cv; cv.h = h; return cv.u;
}

// ------- fp32 -> bf16 convert + transpose, 64x64 tiles: x[b][c][s] -> xs[b][s][c]
__global__ __launch_bounds__(256) void tr64_f32_bf16(const float* __restrict__ in,
                                                     u16* __restrict__ out,
                                                     int R, int Cc) {
  __shared__ u16 tile[64][72];
  int bz = blockIdx.z;
  const float* inb = in + (size_t)bz * R * Cc;
  u16* outb = out + (size_t)bz * R * Cc;
  int c0 = blockIdx.x * 64, r0 = blockIdx.y * 64;
  int tx = threadIdx.x, ty = threadIdx.y;  // 16 x 16
#pragma unroll
  for (int i = 0; i < 4; i++) {
    int r = ty + 16 * i;
    float4 v = *(const float4*)&inb[(size_t)(r0 + r) * Cc + c0 + tx * 4];
    tile[tx * 4 + 0][r] = f2b(v.x);
    tile[tx * 4 + 1][r] = f2b(v.y);
    tile[tx * 4 + 2][r] = f2b(v.z);
    tile[tx * 4 + 3][r] = f2b(v.w);
  }
  __syncthreads();
#pragma unroll
  for (int i = 0; i < 4; i++) {
    int cc = ty + 16 * i;
    ushort4 o = *(ushort4*)&tile[cc][tx * 4];
    *(ushort4*)&outb[(size_t)(c0 + cc) * R + r0 + tx * 4] = o;
  }
}

// ---------------- QKV projection GEMM (R9 verbatim).
__global__ __launch_bounds__(256) void qkv_gemm(const u16* __restrict__ xs,
                                                const float* __restrict__ wq,
                                                const float* __restrict__ bias,
                                                u16* __restrict__ Qo,
                                                u16* __restrict__ Ko,
                                                u16* __restrict__ Vto) {
  __shared__ u16 As[128 * 32];
  __shared__ u16 Bs[128 * 40];
  const int tid = threadIdx.x, wave = tid >> 6, lane = tid & 63;
  const int l15 = lane & 15, quad = lane >> 4;
  const int wm = (wave >> 1) * 64, wn = (wave & 1) * 64;
  const int m0 = blockIdx.x * 128, n0 = blockIdx.y * 128;
  const int bb = m0 >> 10, s0 = m0 & 1023;
  const int srow = wave * 32 + (lane >> 2), scol = (lane & 3) * 8;  // A staging
  const int cl = tid >> 3, u = tid & 7;                             // B staging

  floatx4 acc[4][4] = {};

  for (int kt = 0; kt < 256; kt += 32) {
#pragma unroll
    for (int i = 0; i < 2; i++) {
      int r = srow + i * 16;
      *(short8*)&As[r * 32 + scol] =
          *(const short8*)&xs[((size_t)(bb * 1024 + s0 + r)) * 256 + kt + scol];
    }
    const float* wr = wq + (size_t)(kt + cl) * 768 + n0;
#pragma unroll
    for (int j = 0; j < 4; j++) {
      int e = u * 4 + 32 * j;
      float4 vb = *(const float4*)&wr[e];
      Bs[(e + 0) * 40 + cl] = f2b(vb.x);
      Bs[(e + 1) * 40 + cl] = f2b(vb.y);
      Bs[(e + 2) * 40 + cl] = f2b(vb.z);
      Bs[(e + 3) * 40 + cl] = f2b(vb.w);
    }
    __syncthreads();
    short8 af[4], bfr[4];
#pragma unroll
    for (int mi = 0; mi < 4; mi++)
      af[mi] = *(short8*)&As[(wm + mi * 16 + l15) * 32 + quad * 8];
#pragma unroll
    for (int ni = 0; ni < 4; ni++)
      bfr[ni] = *(short8*)&Bs[(wn + ni * 16 + l15) * 40 + quad * 8];
#pragma unroll
    for (int mi = 0; mi < 4; mi++)
#pragma unroll
      for (int ni = 0; ni < 4; ni++)
        acc[mi][ni] = __builtin_amdgcn_mfma_f32_16x16x32_bf16(af[mi], bfr[ni],
                                                              acc[mi][ni], 0, 0, 0);
    __syncthreads();
  }

#pragma unroll
  for (int ni = 0; ni < 4; ni++) {
    int n = n0 + wn + ni * 16 + l15;
    float bvv = bias[n];
    int h = n / 192;
    int rem = n - h * 192;
#pragma unroll
    for (int mi = 0; mi < 4; mi++) {
      int gm = m0 + wm + mi * 16 + quad * 4;
      int s = gm & 1023;
      if (rem < 128) {
        u16* dst;
        float scl;
        if (rem < 64) { dst = Qo; scl = SCL_LOG2E; } else { dst = Ko; scl = 1.0f; }
        int d = rem & 63;
#pragma unroll
        for (int r = 0; r < 4; r++)
          dst[((size_t)(bb * 4 + h) * 1024 + s + r) * 64 + d] =
              f2b((acc[mi][ni][r] + bvv) * scl);
      } else {
        int d = rem - 128;
        ushort4 pk;
        pk.x = f2b(acc[mi][ni][0] + bvv);
        pk.y = f2b(acc[mi][ni][1] + bvv);
        pk.z = f2b(acc[mi][ni][2] + bvv);
        pk.w = f2b(acc[mi][ni][3] + bvv);
        *(ushort4*)&Vto[((size_t)(bb * 4 + h) * 64 + d) * 1024 + s] = pk;
      }
    }
  }
}

// ---------------- flash attention (R6/R9 verbatim, 128 q-rows per block).
__global__ __launch_bounds__(256, 2) void attn_kern(const u16* __restrict__ Q,
                                                    const u16* __restrict__ K,
                                                    const u16* __restrict__ Vt,
                                                    u16* __restrict__ O) {
  __shared__ u16 kv[2 * 2 * 64 * 72];
  const int bh = blockIdx.y;
  const u16* Qp = Q + (size_t)bh * 64 * 1024;
  const u16* Kp = K + (size_t)bh * 64 * 1024;
  const u16* Vp = Vt + (size_t)bh * 64 * 1024;
  u16* Op = O + (size_t)bh * 64 * 1024;
  const int q0 = blockIdx.x * 128;
  const int tid = threadIdx.x, wave = tid >> 6, lane = tid & 63;
  const int l15 = lane & 15, quad = lane >> 4;

  short8 qa[2][2];
#pragma unroll
  for (int qi = 0; qi < 2; qi++)
#pragma unroll
    for (int kh = 0; kh < 2; kh++)
      qa[qi][kh] = *(const short8*)&Qp[(size_t)(q0 + wave * 32 + qi * 16 + l15) * 64 +
                                       kh * 32 + quad * 8];

  const int srow = tid >> 2;
  const int sc = (tid & 3) * 16;

  {
    short8 k0 = *(const short8*)&Kp[(size_t)srow * 64 + sc];
    short8 k1 = *(const short8*)&Kp[(size_t)srow * 64 + sc + 8];
    short8 v0 = *(const short8*)&Vp[(size_t)srow * 1024 + sc];
    short8 v1 = *(const short8*)&Vp[(size_t)srow * 1024 + sc + 8];
    *(short8*)&kv[srow * 72 + sc] = k0;
    *(short8*)&kv[srow * 72 + sc + 8] = k1;
    *(short8*)&kv[4608 + srow * 72 + sc] = v0;
    *(short8*)&kv[4608 + srow * 72 + sc + 8] = v1;
  }
  __syncthreads();

  float lsum[2] = {0.f, 0.f};
  floatx4 acc[2][4] = {};

  for (int t = 0; t < 16; t++) {
    const u16* Ksb = kv + (t & 1) * 9216;
    const u16* Vsb = Ksb + 4608;

    short8 nk0, nk1, nv0, nv1;
    if (t < 15) {
      nk0 = *(const short8*)&Kp[(size_t)((t + 1) * 64 + srow) * 64 + sc];
      nk1 = *(const short8*)&Kp[(size_t)((t + 1) * 64 + srow) * 64 + sc + 8];
      nv0 = *(const short8*)&Vp[(size_t)srow * 1024 + (t + 1) * 64 + sc];
      nv1 = *(const short8*)&Vp[(size_t)srow * 1024 + (t + 1) * 64 + sc + 8];
    }

    short8 kb[4][2];
#pragma unroll
    for (int mj = 0; mj < 4; mj++)
#pragma unroll
      for (int kh = 0; kh < 2; kh++)
        kb[mj][kh] = *(const short8*)&Ksb[(mj * 16 + l15) * 72 + kh * 32 + quad * 8];

    floatx4 sf[2][4];
#pragma unroll
    for (int qi = 0; qi < 2; qi++)
#pragma unroll
      for (int mj = 0; mj < 4; mj++) {
        floatx4 z = {};
        z = __builtin_amdgcn_mfma_f32_16x16x32_bf16(kb[mj][0], qa[qi][0], z, 0, 0, 0);
        sf[qi][mj] =
            __builtin_amdgcn_mfma_f32_16x16x32_bf16(kb[mj][1], qa[qi][1], z, 0, 0, 0);
      }

    short4v pb[2][4];
#pragma unroll
    for (int qi = 0; qi < 2; qi++)
#pragma unroll
      for (int mj = 0; mj < 4; mj++) {
        float p0 = exp2f(sf[qi][mj][0]), p1 = exp2f(sf[qi][mj][1]);
        float p2 = exp2f(sf[qi][mj][2]), p3 = exp2f(sf[qi][mj][3]);
        lsum[qi] += (p0 + p1) + (p2 + p3);
        short4v pk;
        pk[0] = (short)f2b(p0); pk[1] = (short)f2b(p1);
        pk[2] = (short)f2b(p2); pk[3] = (short)f2b(p3);
        pb[qi][mj] = pk;
      }

#pragma unroll
    for (int c = 0; c < 4; c++)
#pragma unroll
      for (int md = 0; md < 4; md++) {
        short4v va = *(const short4v*)&Vsb[(md * 16 + l15) * 72 + c * 16 + quad * 4];
#pragma unroll
        for (int qi = 0; qi < 2; qi++)
          acc[qi][md] =
              __builtin_amdgcn_mfma_f32_16x16x16bf16_1k(va, pb[qi][c], acc[qi][md],
                                                        0, 0, 0);
      }

    if (t < 15) {
      u16* dst = kv + ((t + 1) & 1) * 9216;
      *(short8*)&dst[srow * 72 + sc] = nk0;
      *(short8*)&dst[srow * 72 + sc + 8] = nk1;
      *(short8*)&dst[4608 + srow * 72 + sc] = nv0;
      *(short8*)&dst[4608 + srow * 72 + sc + 8] = nv1;
    }
    __syncthreads();
  }

  float inv[2];
#pragma unroll
  for (int qi = 0; qi < 2; qi++) {
    lsum[qi] += __shfl_xor(lsum[qi], 16, 64);
    lsum[qi] += __shfl_xor(lsum[qi], 32, 64);
    inv[qi] = 1.f / lsum[qi];
  }

  __syncthreads();
  u16* Ot = kv;
#pragma unroll
  for (int qi = 0; qi < 2; qi++)
#pragma unroll
    for (int md = 0; md < 4; md++) {
      uint2 pk;
      u16 a0 = f2b(acc[qi][md][0] * inv[qi]), a1 = f2b(acc[qi][md][1] * inv[qi]);
      u16 a2 = f2b(acc[qi][md][2] * inv[qi]), a3 = f2b(acc[qi][md][3] * inv[qi]);
      pk.x = (unsigned)a0 | ((unsigned)a1 << 16);
      pk.y = (unsigned)a2 | ((unsigned)a3 << 16);
      *(uint2*)&Ot[(wave * 32 + qi * 16 + l15) * 72 + md * 16 + quad * 4] = pk;
    }
  __syncthreads();
#pragma unroll
  for (int rr = 0; rr < 4; rr++) {
    int row = wave * 32 + (lane >> 3) + 8 * rr;
    int col = (lane & 7) * 8;
    short8 v = *(const short8*)&Ot[row * 72 + col];
    *(short8*)&Op[(size_t)(q0 + row) * 64 + col] = v;
  }
}

// ---------------- output projection + bias + fp32 residual (R9 verbatim).
__global__ __launch_bounds__(256) void out_gemm(const u16* __restrict__ Oin,
                                                const float* __restrict__ wo,
                                                const float* __restrict__ bias,
                                                const float* __restrict__ x,
                                                float* __restrict__ out) {
  __shared__ u16 As[64 * 32];
  __shared__ u16 Bs[128 * 40];
  const int tid = threadIdx.x, wave = tid >> 6, lane = tid & 63;
  const int l15 = lane & 15, quad = lane >> 4;
  const int wm = (wave >> 1) * 32, wn = (wave & 1) * 64;
  const int m0 = blockIdx.x * 64, n0 = blockIdx.y * 128;
  const int bb = m0 >> 10, s0 = m0 & 1023;
  const int ar = tid >> 2, ach = (tid & 3) * 8;  // A staging
  const int cl = tid >> 3, u = tid & 7;          // B staging

  floatx4 acc[2][4] = {};

  for (int kt = 0; kt < 256; kt += 32) {
    int h = kt >> 6, d0 = kt & 63;
    *(short8*)&As[ar * 32 + ach] =
        *(const short8*)&Oin[((size_t)(bb * 4 + h) * 1024 + s0 + ar) * 64 + d0 + ach];
    const float* wr = wo + (size_t)(kt + cl) * 256 + n0;
#pragma unroll
    for (int j = 0; j < 4; j++) {
      int e = u * 4 + 32 * j;
      float4 vb = *(const float4*)&wr[e];
      Bs[(e + 0) * 40 + cl] = f2b(vb.x);
      Bs[(e + 1) * 40 + cl] = f2b(vb.y);
      Bs[(e + 2) * 40 + cl] = f2b(vb.z);
      Bs[(e + 3) * 40 + cl] = f2b(vb.w);
    }
    __syncthreads();
    short8 af[2], bfr[4];
#pragma unroll
    for (int mi = 0; mi < 2; mi++)
      af[mi] = *(short8*)&As[(wm + mi * 16 + l15) * 32 + quad * 8];
#pragma unroll
    for (int ni = 0; ni < 4; ni++)
      bfr[ni] = *(short8*)&Bs[(wn + ni * 16 + l15) * 40 + quad * 8];
#pragma unroll
    for (int mi = 0; mi < 2; mi++)
#pragma unroll
      for (int ni = 0; ni < 4; ni++)
        acc[mi][ni] = __builtin_amdgcn_mfma_f32_16x16x32_bf16(af[mi], bfr[ni],
                                                              acc[mi][ni], 0, 0, 0);
    __syncthreads();
  }

#pragma unroll
  for (int ni = 0; ni < 4; ni++) {
    int c = n0 + wn + ni * 16 + l15;
    float bvv = bias[c];
#pragma unroll
    for (int mi = 0; mi < 2; mi++) {
      int gm = m0 + wm + mi * 16 + quad * 4;
      int s = gm & 1023;
      size_t idx = ((size_t)bb * 256 + c) * 1024 + s;
      float4 xr = *(const float4*)&x[idx];
      float4 o;
      o.x = acc[mi][ni][0] + bvv + xr.x;
      o.y = acc[mi][ni][1] + bvv + xr.y;
      o.z = acc[mi][ni][2] + bvv + xr.z;
      o.w = acc[mi][ni][3] + bvv + xr.w;
      *(float4*)&out[idx] = o;
    }
  }
}

extern "C" void kernel_launch(void* const* d_in, const int* in_sizes, int n_in,
                              void* d_out, int out_size, void* d_ws, size_t ws_size,
                              hipStream_t stream) {
  const float* x     = (const float*)d_in[0];
  const float* w_qkv = (const float*)d_in[1];
  const float* b_qkv = (const float*)d_in[2];
  const float* w_out = (const float*)d_in[3];
  const float* b_out = (const float*)d_in[4];
  float* out = (float*)d_out;
  char* ws = (char*)d_ws;

  u16* xs  = (u16*)(ws);             // 8 MB  [b][s][c] bf16
  u16* Qb  = (u16*)(ws + 8388608);   // 8 MB
  u16* Kb  = (u16*)(ws + 16777216);  // 8 MB
  u16* Vtb = (u16*)(ws + 25165824);  // 8 MB
  u16* Ob  = xs;                     // xs dead after qkv_gemm

  tr64_f32_bf16<<<dim3(16, 4, 16), dim3(16, 16), 0, stream>>>(x, xs, 256, 1024);
  qkv_gemm<<<dim3(128, 6), 256, 0, stream>>>(xs, w_qkv, b_qkv, Qb, Kb, Vtb);
  // MEASUREMENT: attn launched twice (idempotent — reads Q/K/V, rewrites identical O).
  // Delta vs R9 total isolates attn's true duration.
  attn_kern<<<dim3(8, 64), 256, 0, stream>>>(Qb, Kb, Vtb, Ob);
  attn_kern<<<dim3(8, 64), 256, 0, stream>>>(Qb, Kb, Vtb, Ob);
  out_gemm<<<dim3(256, 2), 256, 0, stream>>>(Ob, w_out, b_out, x, out);
}

// Round 11
// 141.353 us; speedup vs baseline: 1.2665x; 1.2665x over previous
//
#include <hip/hip_runtime.h>
#include <hip/hip_bf16.h>

typedef __attribute__((ext_vector_type(8))) short short8;
typedef __attribute__((ext_vector_type(4))) short short4v;
typedef __attribute__((ext_vector_type(4))) float floatx4;
typedef unsigned short u16;

#define SCL_LOG2E 0.1803368801111204f  // (1/sqrt(64)) * log2(e)

__device__ inline u16 f2b(float f) {
  __hip_bfloat16 h = __float2bfloat16(f);
  union { __hip_bfloat16 h; u16 u; } cv; cv.h = h; return cv.u;
}

// ------- fp32 -> bf16 convert + transpose, 64x64 tiles: x[b][c][s] -> xs[b][s][c]
__global__ __launch_bounds__(256) void tr64_f32_bf16(const float* __restrict__ in,
                                                     u16* __restrict__ out,
                                                     int R, int Cc) {
  __shared__ u16 tile[64][72];
  int bz = blockIdx.z;
  const float* inb = in + (size_t)bz * R * Cc;
  u16* outb = out + (size_t)bz * R * Cc;
  int c0 = blockIdx.x * 64, r0 = blockIdx.y * 64;
  int tx = threadIdx.x, ty = threadIdx.y;  // 16 x 16
#pragma unroll
  for (int i = 0; i < 4; i++) {
    int r = ty + 16 * i;
    float4 v = *(const float4*)&inb[(size_t)(r0 + r) * Cc + c0 + tx * 4];
    tile[tx * 4 + 0][r] = f2b(v.x);
    tile[tx * 4 + 1][r] = f2b(v.y);
    tile[tx * 4 + 2][r] = f2b(v.z);
    tile[tx * 4 + 3][r] = f2b(v.w);
  }
  __syncthreads();
#pragma unroll
  for (int i = 0; i < 4; i++) {
    int cc = ty + 16 * i;
    ushort4 o = *(ushort4*)&tile[cc][tx * 4];
    *(ushort4*)&outb[(size_t)(c0 + cc) * R + r0 + tx * 4] = o;
  }
}

// ---------------- QKV projection GEMM (R9 verbatim).
__global__ __launch_bounds__(256) void qkv_gemm(const u16* __restrict__ xs,
                                                const float* __restrict__ wq,
                                                const float* __restrict__ bias,
                                                u16* __restrict__ Qo,
                                                u16* __restrict__ Ko,
                                                u16* __restrict__ Vto) {
  __shared__ u16 As[128 * 32];
  __shared__ u16 Bs[128 * 40];
  const int tid = threadIdx.x, wave = tid >> 6, lane = tid & 63;
  const int l15 = lane & 15, quad = lane >> 4;
  const int wm = (wave >> 1) * 64, wn = (wave & 1) * 64;
  const int m0 = blockIdx.x * 128, n0 = blockIdx.y * 128;
  const int bb = m0 >> 10, s0 = m0 & 1023;
  const int srow = wave * 32 + (lane >> 2), scol = (lane & 3) * 8;  // A staging
  const int cl = tid >> 3, u = tid & 7;                             // B staging

  floatx4 acc[4][4] = {};

  for (int kt = 0; kt < 256; kt += 32) {
#pragma unroll
    for (int i = 0; i < 2; i++) {
      int r = srow + i * 16;
      *(short8*)&As[r * 32 + scol] =
          *(const short8*)&xs[((size_t)(bb * 1024 + s0 + r)) * 256 + kt + scol];
    }
    const float* wr = wq + (size_t)(kt + cl) * 768 + n0;
#pragma unroll
    for (int j = 0; j < 4; j++) {
      int e = u * 4 + 32 * j;
      float4 vb = *(const float4*)&wr[e];
      Bs[(e + 0) * 40 + cl] = f2b(vb.x);
      Bs[(e + 1) * 40 + cl] = f2b(vb.y);
      Bs[(e + 2) * 40 + cl] = f2b(vb.z);
      Bs[(e + 3) * 40 + cl] = f2b(vb.w);
    }
    __syncthreads();
    short8 af[4], bfr[4];
#pragma unroll
    for (int mi = 0; mi < 4; mi++)
      af[mi] = *(short8*)&As[(wm + mi * 16 + l15) * 32 + quad * 8];
#pragma unroll
    for (int ni = 0; ni < 4; ni++)
      bfr[ni] = *(short8*)&Bs[(wn + ni * 16 + l15) * 40 + quad * 8];
#pragma unroll
    for (int mi = 0; mi < 4; mi++)
#pragma unroll
      for (int ni = 0; ni < 4; ni++)
        acc[mi][ni] = __builtin_amdgcn_mfma_f32_16x16x32_bf16(af[mi], bfr[ni],
                                                              acc[mi][ni], 0, 0, 0);
    __syncthreads();
  }

#pragma unroll
  for (int ni = 0; ni < 4; ni++) {
    int n = n0 + wn + ni * 16 + l15;
    float bvv = bias[n];
    int h = n / 192;
    int rem = n - h * 192;
#pragma unroll
    for (int mi = 0; mi < 4; mi++) {
      int gm = m0 + wm + mi * 16 + quad * 4;
      int s = gm & 1023;
      if (rem < 128) {
        u16* dst;
        float scl;
        if (rem < 64) { dst = Qo; scl = SCL_LOG2E; } else { dst = Ko; scl = 1.0f; }
        int d = rem & 63;
#pragma unroll
        for (int r = 0; r < 4; r++)
          dst[((size_t)(bb * 4 + h) * 1024 + s + r) * 64 + d] =
              f2b((acc[mi][ni][r] + bvv) * scl);
      } else {
        int d = rem - 128;
        ushort4 pk;
        pk.x = f2b(acc[mi][ni][0] + bvv);
        pk.y = f2b(acc[mi][ni][1] + bvv);
        pk.z = f2b(acc[mi][ni][2] + bvv);
        pk.w = f2b(acc[mi][ni][3] + bvv);
        *(ushort4*)&Vto[((size_t)(bb * 4 + h) * 64 + d) * 1024 + s] = pk;
      }
    }
  }
}

// ---------------- flash attention: tri-buffered K/V pipeline (prefetch dist 2),
// XCD-pinned grid (bh on blockIdx.x; 8 q-blocks per bh at id-stride 64 == same XCD).
// Transposed formulation as R9: S^T = K·Q^T; exp2(S^T) feeds O^T = V^T·P^T directly.
__global__ __launch_bounds__(256, 2) void attn_kern(const u16* __restrict__ Q,
                                                    const u16* __restrict__ K,
                                                    const u16* __restrict__ Vt,
                                                    u16* __restrict__ O) {
  __shared__ u16 kv[3 * 2 * 64 * 72];  // 3 bufs x (K 4608 + V 4608) u16 = 54 KB
  const int bh = blockIdx.x;
  const u16* Qp = Q + (size_t)bh * 64 * 1024;
  const u16* Kp = K + (size_t)bh * 64 * 1024;
  const u16* Vp = Vt + (size_t)bh * 64 * 1024;
  u16* Op = O + (size_t)bh * 64 * 1024;
  const int q0 = blockIdx.y * 128;
  const int tid = threadIdx.x, wave = tid >> 6, lane = tid & 63;
  const int l15 = lane & 15, quad = lane >> 4;

  short8 qa[2][2];
#pragma unroll
  for (int qi = 0; qi < 2; qi++)
#pragma unroll
    for (int kh = 0; kh < 2; kh++)
      qa[qi][kh] = *(const short8*)&Qp[(size_t)(q0 + wave * 32 + qi * 16 + l15) * 64 +
                                       kh * 32 + quad * 8];

  const int srow = tid >> 2;
  const int sc = (tid & 3) * 16;
  const size_t kRow = (size_t)srow * 64 + sc;      // K tile row base (advance by 64*64)
  const size_t vRow = (size_t)srow * 1024 + sc;    // V row base (advance by 64)

  // prologue: tiles 0,1 -> buf0,buf1; tile 2 loads -> regs r1
  short8 t0k0 = *(const short8*)&Kp[kRow];
  short8 t0k1 = *(const short8*)&Kp[kRow + 8];
  short8 t0v0 = *(const short8*)&Vp[vRow];
  short8 t0v1 = *(const short8*)&Vp[vRow + 8];
  short8 t1k0 = *(const short8*)&Kp[kRow + 4096];
  short8 t1k1 = *(const short8*)&Kp[kRow + 4096 + 8];
  short8 t1v0 = *(const short8*)&Vp[vRow + 64];
  short8 t1v1 = *(const short8*)&Vp[vRow + 64 + 8];
  short8 r1k0 = *(const short8*)&Kp[kRow + 8192];
  short8 r1k1 = *(const short8*)&Kp[kRow + 8192 + 8];
  short8 r1v0 = *(const short8*)&Vp[vRow + 128];
  short8 r1v1 = *(const short8*)&Vp[vRow + 128 + 8];
  *(short8*)&kv[srow * 72 + sc] = t0k0;
  *(short8*)&kv[srow * 72 + sc + 8] = t0k1;
  *(short8*)&kv[4608 + srow * 72 + sc] = t0v0;
  *(short8*)&kv[4608 + srow * 72 + sc + 8] = t0v1;
  *(short8*)&kv[9216 + srow * 72 + sc] = t1k0;
  *(short8*)&kv[9216 + srow * 72 + sc + 8] = t1k1;
  *(short8*)&kv[9216 + 4608 + srow * 72 + sc] = t1v0;
  *(short8*)&kv[9216 + 4608 + srow * 72 + sc + 8] = t1v1;
  __syncthreads();

  float lsum[2] = {0.f, 0.f};
  floatx4 acc[2][4] = {};

  int cur = 0;   // buffer holding tile t
  int wr = 2;    // buffer to write tile t+2 into
  for (int t = 0; t < 16; t++) {
    const u16* Ksb = kv + cur * 9216;
    const u16* Vsb = Ksb + 4608;

    short8 r2k0, r2k1, r2v0, r2v1;
    if (t < 13) {  // issue loads for tile t+3 (waited at end of t+1)
      size_t ko = kRow + (size_t)(t + 3) * 4096;
      size_t vo = vRow + (size_t)(t + 3) * 64;
      r2k0 = *(const short8*)&Kp[ko];
      r2k1 = *(const short8*)&Kp[ko + 8];
      r2v0 = *(const short8*)&Vp[vo];
      r2v1 = *(const short8*)&Vp[vo + 8];
    }

    short8 kb[4][2];
#pragma unroll
    for (int mj = 0; mj < 4; mj++)
#pragma unroll
      for (int kh = 0; kh < 2; kh++)
        kb[mj][kh] = *(const short8*)&Ksb[(mj * 16 + l15) * 72 + kh * 32 + quad * 8];

    floatx4 sf[2][4];
#pragma unroll
    for (int qi = 0; qi < 2; qi++)
#pragma unroll
      for (int mj = 0; mj < 4; mj++) {
        floatx4 z = {};
        z = __builtin_amdgcn_mfma_f32_16x16x32_bf16(kb[mj][0], qa[qi][0], z, 0, 0, 0);
        sf[qi][mj] =
            __builtin_amdgcn_mfma_f32_16x16x32_bf16(kb[mj][1], qa[qi][1], z, 0, 0, 0);
      }

    short4v pb[2][4];
#pragma unroll
    for (int qi = 0; qi < 2; qi++)
#pragma unroll
      for (int mj = 0; mj < 4; mj++) {
        float p0 = exp2f(sf[qi][mj][0]), p1 = exp2f(sf[qi][mj][1]);
        float p2 = exp2f(sf[qi][mj][2]), p3 = exp2f(sf[qi][mj][3]);
        lsum[qi] += (p0 + p1) + (p2 + p3);
        short4v pk;
        pk[0] = (short)f2b(p0); pk[1] = (short)f2b(p1);
        pk[2] = (short)f2b(p2); pk[3] = (short)f2b(p3);
        pb[qi][mj] = pk;
      }

#pragma unroll
    for (int c = 0; c < 4; c++)
#pragma unroll
      for (int md = 0; md < 4; md++) {
        short4v va = *(const short4v*)&Vsb[(md * 16 + l15) * 72 + c * 16 + quad * 4];
#pragma unroll
        for (int qi = 0; qi < 2; qi++)
          acc[qi][md] =
              __builtin_amdgcn_mfma_f32_16x16x16bf16_1k(va, pb[qi][c], acc[qi][md],
                                                        0, 0, 0);
      }

    if (t < 14) {  // write tile t+2 (loads issued at iteration t-1) into buf wr
      u16* dst = kv + wr * 9216;
      *(short8*)&dst[srow * 72 + sc] = r1k0;
      *(short8*)&dst[srow * 72 + sc + 8] = r1k1;
      *(short8*)&dst[4608 + srow * 72 + sc] = r1v0;
      *(short8*)&dst[4608 + srow * 72 + sc + 8] = r1v1;
    }
    r1k0 = r2k0; r1k1 = r2k1; r1v0 = r2v0; r1v1 = r2v1;
    cur = (cur == 2) ? 0 : cur + 1;
    wr = (wr == 2) ? 0 : wr + 1;
    __syncthreads();
  }

  float inv[2];
#pragma unroll
  for (int qi = 0; qi < 2; qi++) {
    lsum[qi] += __shfl_xor(lsum[qi], 16, 64);
    lsum[qi] += __shfl_xor(lsum[qi], 32, 64);
    inv[qi] = 1.f / lsum[qi];
  }

  // transpose O^T -> O[s][d] through LDS (reuse kv buffer: 128 x 72 u16)
  u16* Ot = kv;
#pragma unroll
  for (int qi = 0; qi < 2; qi++)
#pragma unroll
    for (int md = 0; md < 4; md++) {
      uint2 pk;
      u16 a0 = f2b(acc[qi][md][0] * inv[qi]), a1 = f2b(acc[qi][md][1] * inv[qi]);
      u16 a2 = f2b(acc[qi][md][2] * inv[qi]), a3 = f2b(acc[qi][md][3] * inv[qi]);
      pk.x = (unsigned)a0 | ((unsigned)a1 << 16);
      pk.y = (unsigned)a2 | ((unsigned)a3 << 16);
      *(uint2*)&Ot[(wave * 32 + qi * 16 + l15) * 72 + md * 16 + quad * 4] = pk;
    }
  __syncthreads();
#pragma unroll
  for (int rr = 0; rr < 4; rr++) {
    int row = wave * 32 + (lane >> 3) + 8 * rr;
    int col = (lane & 7) * 8;
    short8 v = *(const short8*)&Ot[row * 72 + col];
    *(short8*)&Op[(size_t)(q0 + row) * 64 + col] = v;
  }
}

// ---------------- output projection + bias + fp32 residual (R9 verbatim).
__global__ __launch_bounds__(256) void out_gemm(const u16* __restrict__ Oin,
                                                const float* __restrict__ wo,
                                                const float* __restrict__ bias,
                                                const float* __restrict__ x,
                                                float* __restrict__ out) {
  __shared__ u16 As[64 * 32];
  __shared__ u16 Bs[128 * 40];
  const int tid = threadIdx.x, wave = tid >> 6, lane = tid & 63;
  const int l15 = lane & 15, quad = lane >> 4;
  const int wm = (wave >> 1) * 32, wn = (wave & 1) * 64;
  const int m0 = blockIdx.x * 64, n0 = blockIdx.y * 128;
  const int bb = m0 >> 10, s0 = m0 & 1023;
  const int ar = tid >> 2, ach = (tid & 3) * 8;  // A staging
  const int cl = tid >> 3, u = tid & 7;          // B staging

  floatx4 acc[2][4] = {};

  for (int kt = 0; kt < 256; kt += 32) {
    int h = kt >> 6, d0 = kt & 63;
    *(short8*)&As[ar * 32 + ach] =
        *(const short8*)&Oin[((size_t)(bb * 4 + h) * 1024 + s0 + ar) * 64 + d0 + ach];
    const float* wr = wo + (size_t)(kt + cl) * 256 + n0;
#pragma unroll
    for (int j = 0; j < 4; j++) {
      int e = u * 4 + 32 * j;
      float4 vb = *(const float4*)&wr[e];
      Bs[(e + 0) * 40 + cl] = f2b(vb.x);
      Bs[(e + 1) * 40 + cl] = f2b(vb.y);
      Bs[(e + 2) * 40 + cl] = f2b(vb.z);
      Bs[(e + 3) * 40 + cl] = f2b(vb.w);
    }
    __syncthreads();
    short8 af[2], bfr[4];
#pragma unroll
    for (int mi = 0; mi < 2; mi++)
      af[mi] = *(short8*)&As[(wm + mi * 16 + l15) * 32 + quad * 8];
#pragma unroll
    for (int ni = 0; ni < 4; ni++)
      bfr[ni] = *(short8*)&Bs[(wn + ni * 16 + l15) * 40 + quad * 8];
#pragma unroll
    for (int mi = 0; mi < 2; mi++)
#pragma unroll
      for (int ni = 0; ni < 4; ni++)
        acc[mi][ni] = __builtin_amdgcn_mfma_f32_16x16x32_bf16(af[mi], bfr[ni],
                                                              acc[mi][ni], 0, 0, 0);
    __syncthreads();
  }

#pragma unroll
  for (int ni = 0; ni < 4; ni++) {
    int c = n0 + wn + ni * 16 + l15;
    float bvv = bias[c];
#pragma unroll
    for (int mi = 0; mi < 2; mi++) {
      int gm = m0 + wm + mi * 16 + quad * 4;
      int s = gm & 1023;
      size_t idx = ((size_t)bb * 256 + c) * 1024 + s;
      float4 xr = *(const float4*)&x[idx];
      float4 o;
      o.x = acc[mi][ni][0] + bvv + xr.x;
      o.y = acc[mi][ni][1] + bvv + xr.y;
      o.z = acc[mi][ni][2] + bvv + xr.z;
      o.w = acc[mi][ni][3] + bvv + xr.w;
      *(float4*)&out[idx] = o;
    }
  }
}

extern "C" void kernel_launch(void* const* d_in, const int* in_sizes, int n_in,
                              void* d_out, int out_size, void* d_ws, size_t ws_size,
                              hipStream_t stream) {
  const float* x     = (const float*)d_in[0];
  const float* w_qkv = (const float*)d_in[1];
  const float* b_qkv = (const float*)d_in[2];
  const float* w_out = (const float*)d_in[3];
  const float* b_out = (const float*)d_in[4];
  float* out = (float*)d_out;
  char* ws = (char*)d_ws;

  u16* xs  = (u16*)(ws);             // 8 MB  [b][s][c] bf16
  u16* Qb  = (u16*)(ws + 8388608);   // 8 MB
  u16* Kb  = (u16*)(ws + 16777216);  // 8 MB
  u16* Vtb = (u16*)(ws + 25165824);  // 8 MB
  u16* Ob  = xs;                     // xs dead after qkv_gemm

  tr64_f32_bf16<<<dim3(16, 4, 16), dim3(16, 16), 0, stream>>>(x, xs, 256, 1024);
  qkv_gemm<<<dim3(128, 6), 256, 0, stream>>>(xs, w_qkv, b_qkv, Qb, Kb, Vtb);
  attn_kern<<<dim3(64, 8), 256, 0, stream>>>(Qb, Kb, Vtb, Ob);
  out_gemm<<<dim3(256, 2), 256, 0, stream>>>(Ob, w_out, b_out, x, out);
}